// Round 34
// baseline (99.716 us; speedup 1.0000x reference)
//
#include <hip/hip_runtime.h>
#include <math.h>

#define CIN  256
#define COUT 128
#define HW   4096
#define NB   4
#define OCSPLIT 4
#define CSPLIT  2
#define CPC  (CIN / CSPLIT)      // 128 channels per k_dcn block (4 chunks of 32)
#define SFLAV (576 * 16)         // u32 words in k_dcn sbuf (hi flavor only)

typedef short short8v __attribute__((ext_vector_type(8)));
typedef float f32x4  __attribute__((ext_vector_type(4)));

// ---------------- merged weight prep: DCN hi/lo split + offset-conv pack + bias
__global__ __launch_bounds__(256) void k_prep(
    const float* __restrict__ w_dcn, const float* __restrict__ b_dcn,
    const float* __restrict__ gamma, const float* __restrict__ beta,
    const float* __restrict__ rmean, const float* __restrict__ rvar,
    const float* __restrict__ w_off,
    unsigned short* __restrict__ w_hi, unsigned short* __restrict__ w_lo,
    unsigned short* __restrict__ wo_hi, unsigned short* __restrict__ wo_lo,
    float* __restrict__ bias_t)
{
  int t = blockIdx.x * 256 + threadIdx.x;
  if (t < COUT) {
    float sc = gamma[t] * rsqrtf(rvar[t] + 1e-5f);
    bias_t[t] = b_dcn[t] * sc + beta[t] - rmean[t] * sc;
  }
  if (t < 9 * 32 * 32 * 8) {   // offset-conv weights: [k][cq][co32][8ch], co>=27 zero
    int ce = t & 7;
    int co = (t >> 3) & 31;
    int cq = (t >> 8) & 31;
    int k  = t >> 13;
    int c = cq * 8 + ce;
    float w = (co < 27) ? w_off[((size_t)co * CIN + c) * 9 + k] : 0.f;
    unsigned int wb = __float_as_uint(w);
    unsigned short hi = (unsigned short)(wb >> 16);
    float lof = w - __uint_as_float(wb & 0xFFFF0000u);
    unsigned short lo = (unsigned short)(__float_as_uint(lof) >> 16);
    wo_hi[t] = hi;
    wo_lo[t] = lo;
  }
  if (t >= CIN * COUT * 9) return;
  int k = t % 9;
  int q = t / 9;
  int co = q % COUT;
  int c  = q / COUT;
  float sc = gamma[co] * rsqrtf(rvar[co] + 1e-5f);
  float w = w_dcn[((size_t)co * CIN + c) * 9 + k] * sc;
  unsigned int wb = __float_as_uint(w);
  unsigned short hi = (unsigned short)(wb >> 16);
  float lof = w - __uint_as_float(wb & 0xFFFF0000u);
  unsigned short lo = (unsigned short)(__float_as_uint(lof) >> 16);
  size_t idx = (((size_t)k * 32 + (c >> 3)) * 128 + co) * 8 + (c & 7);
  w_hi[idx] = hi;
  w_lo[idx] = lo;
}

// ---------------- offset conv via MFMA: x rounded bf16 (2-term), W hi/lo split
// + XCD swizzle (grid 1024 = 8 x 128). LDS 15840 B.  (R30, validated)
__global__ __launch_bounds__(256, 4) void k_off_mfma(
    const float* __restrict__ x,
    const unsigned short* __restrict__ wo_hi, const unsigned short* __restrict__ wo_lo,
    float* __restrict__ om_part)
{
  int blk = (blockIdx.x & 7) * 128 + (blockIdx.x >> 3);  // bijective: 1024 = 8*128
  int split = blk & 3;
  int bh = blk >> 2;
  int b = bh >> 6, h = bh & 63;
  int t = threadIdx.x;
  int lane = t & 63;
  int wv = t >> 6;
  int lrow = lane & 15, lgrp = lane >> 4;

  __shared__ __align__(16) unsigned int win_hi[3 * 66 * 20];  // 15840 B

  f32x4 acc[2];
  acc[0] = (f32x4){0.f, 0.f, 0.f, 0.f};
  acc[1] = (f32x4){0.f, 0.f, 0.f, 0.f};

  const float* xb = x + (size_t)b * CIN * HW;

  for (int chunk = 0; chunk < 2; ++chunk) {
    int cbase = split * 64 + chunk * 32;
    for (int i = t; i < 3168; i += 256) {
      int cp = i / 198;
      int s  = i - cp * 198;
      int r  = s / 66;
      int colp = s - r * 66;
      int row = h + r - 1;
      int col = colp - 1;
      bool v = ((unsigned)row < 64u) && ((unsigned)col < 64u);
      int ch = cbase + 2 * cp;
      float f0 = 0.f, f1 = 0.f;
      if (v) {
        const float* xp = xb + ((size_t)ch * 64 + row) * 64 + col;
        f0 = xp[0];
        f1 = xp[HW];
      }
      unsigned a0 = __float_as_uint(f0) + 0x8000u;   // round-to-nearest bf16
      unsigned a1 = __float_as_uint(f1) + 0x8000u;
      win_hi[s * 20 + cp] = (a0 >> 16) | (a1 & 0xFFFF0000u);
    }
    __syncthreads();

    int pos = wv * 16 + lrow;
#pragma unroll
    for (int k = 0; k < 9; ++k) {
      int ky = k / 3 - 1, kx = k % 3 - 1;
      int slot = (ky + 1) * 66 + pos + kx + 1;
      short8v bhv = *(const short8v*)&win_hi[slot * 20 + lgrp * 4];
#pragma unroll
      for (int m = 0; m < 2; ++m) {
        size_t widx = (((size_t)k * 32 + (cbase >> 3) + lgrp) * 32 + m * 16 + lrow) * 8;
        short8v ah = *(const short8v*)(wo_hi + widx);
        short8v al = *(const short8v*)(wo_lo + widx);
        acc[m] = __builtin_amdgcn_mfma_f32_16x16x32_bf16(ah, bhv, acc[m], 0, 0, 0);
        acc[m] = __builtin_amdgcn_mfma_f32_16x16x32_bf16(al, bhv, acc[m], 0, 0, 0);
      }
    }
    __syncthreads();
  }

  int pos = wv * 16 + lrow;
#pragma unroll
  for (int m = 0; m < 2; ++m)
#pragma unroll
    for (int j = 0; j < 4; ++j) {
      int co = m * 16 + lgrp * 4 + j;
      if (co < 27)
        om_part[(((size_t)split * NB + b) * 27 + co) * HW + h * 64 + pos] = acc[m][j];
    }
}

// ---------------- DCN: P=64 channel-last LDS window + MFMA
// 8-channel staging steps (4/chunk): barriers 17 -> 9 per chunk at same occupancy.
// S rounded bf16 (2-term MFMA), inline md, XCD swizzle. LDS 53248 B.
__global__ __launch_bounds__(256, 3) void k_dcn(
    const float* __restrict__ x,
    const unsigned short* __restrict__ w_hi, const unsigned short* __restrict__ w_lo,
    const float* __restrict__ om_part, const float* __restrict__ b_off,
    float* __restrict__ part)
{
  int blk = (blockIdx.x & 7) * 64 + (blockIdx.x >> 3);  // bijective: 512 = 8*64
  int h = blk & 63;
  int b = (blk >> 6) & (NB - 1);
  int s2 = blk >> 8;
  int c0 = s2 * CPC;
  int t = threadIdx.x;
  int lane = t & 63;
  int wv = t >> 6;
  int lrow = lane & 15, lgrp = lane >> 4;

  __shared__ __align__(16) unsigned int sbuf[SFLAV];      // 36864 B (hi only)
  __shared__ __align__(16) float win[8 * 64 * 8];         // 16384 B, channel-last x8

  int W0 = min(max(h - 3, 0), 56);
  int ob = W0 * 64;

#define MDCALC(K, POS, MW, MI)                                                  \
  {                                                                             \
    int k_ = (K);                                                               \
    int hw_ = h * 64 + (POS);                                                   \
    int w_ = hw_ & 63;                                                          \
    float dy = b_off[2 * k_], dx = b_off[2 * k_ + 1], mr = b_off[18 + k_];      \
    _Pragma("unroll")                                                           \
    for (int s_ = 0; s_ < OCSPLIT; ++s_) {                                      \
      size_t o_ = ((size_t)s_ * NB + b) * 27 * HW + hw_;                        \
      dy += om_part[o_ + (size_t)(2 * k_) * HW];                                \
      dx += om_part[o_ + (size_t)(2 * k_ + 1) * HW];                            \
      mr += om_part[o_ + (size_t)(18 + k_) * HW];                               \
    }                                                                           \
    float m_ = 1.0f / (1.0f + expf(-mr));                                       \
    int ky_ = k_ / 3 - 1, kx_ = k_ % 3 - 1;                                     \
    float py_ = dy + (float)h + (float)ky_;                                     \
    float px_ = dx + (float)w_ + (float)kx_;                                    \
    float y0f_ = floorf(py_), x0f_ = floorf(px_);                               \
    float fy_ = py_ - y0f_, fx_ = px_ - x0f_;                                   \
    int y0_ = (int)y0f_, x0_ = (int)x0f_;                                       \
    int y1_ = y0_ + 1, x1_ = x0_ + 1;                                           \
    bool vy0_ = (y0_ >= 0) & (y0_ < 64), vy1_ = (y1_ >= 0) & (y1_ < 64);        \
    bool vx0_ = (x0_ >= 0) & (x0_ < 64), vx1_ = (x1_ >= 0) & (x1_ < 64);        \
    int cy0_ = min(max(y0_, 0), 63), cy1_ = min(max(y1_, 0), 63);               \
    int cx0_ = min(max(x0_, 0), 63), cx1_ = min(max(x1_, 0), 63);               \
    MW.x = (vy0_ && vx0_) ? (1.f - fy_) * (1.f - fx_) * m_ : 0.f;               \
    MW.y = (vy0_ && vx1_) ? (1.f - fy_) * fx_ * m_ : 0.f;                       \
    MW.z = (vy1_ && vx0_) ? fy_ * (1.f - fx_) * m_ : 0.f;                       \
    MW.w = (vy1_ && vx1_) ? fy_ * fx_ * m_ : 0.f;                               \
    MI.x = cy0_ * 64 + cx0_;                                                    \
    MI.y = cy0_ * 64 + cx1_;                                                    \
    MI.z = cy1_ * 64 + cx0_;                                                    \
    MI.w = cy1_ * 64 + cx1_;                                                    \
  }

  int k0 = t >> 6;
  float4 mw0; int4 mi0;
  float4 mw1; int4 mi1;
  MDCALC(k0, (t & 63), mw0, mi0)
  MDCALC(k0 + 4, (t & 63), mw1, mi1)
  bool hasC = (t < 64);
  float4 mw2 = make_float4(0.f, 0.f, 0.f, 0.f);
  int4  mi2 = make_int4(0, 0, 0, 0);
  if (hasC) MDCALC(8, t, mw2, mi2)
#undef MDCALC

  int fast0 = __all(((unsigned)(mi0.x - ob) < 512u) && ((unsigned)(mi0.z - ob) < 512u));
  int fast1 = __all(((unsigned)(mi1.x - ob) < 512u) && ((unsigned)(mi1.z - ob) < 512u));
  int fast2 = __all(((unsigned)(mi2.x - ob) < 512u) && ((unsigned)(mi2.z - ob) < 512u));

  f32x4 acc[2][4];
#pragma unroll
  for (int m = 0; m < 2; ++m)
#pragma unroll
    for (int nt = 0; nt < 4; ++nt)
      acc[m][nt] = (f32x4){0.f, 0.f, 0.f, 0.f};

  const float* xb = x + (size_t)b * CIN * HW;

// 8-channel gather: 2 float4 taps each, pack to one aligned uint4 (RTN bf16 pairs)
#define GATHER(MW, MI, FASTE, ROW)                                              \
  {                                                                             \
    float s0_, s1_, s2_, s3_, s4_, s5_, s6_, s7_;                               \
    if (FASTE) {                                                                \
      float4 A0 = *(const float4*)&win[(MI.x - ob) * 8];                        \
      float4 A1 = *(const float4*)&win[(MI.x - ob) * 8 + 4];                    \
      float4 B0 = *(const float4*)&win[(MI.y - ob) * 8];                        \
      float4 B1 = *(const float4*)&win[(MI.y - ob) * 8 + 4];                    \
      float4 C0 = *(const float4*)&win[(MI.z - ob) * 8];                        \
      float4 C1 = *(const float4*)&win[(MI.z - ob) * 8 + 4];                    \
      float4 D0 = *(const float4*)&win[(MI.w - ob) * 8];                        \
      float4 D1 = *(const float4*)&win[(MI.w - ob) * 8 + 4];                    \
      s0_ = MW.x * A0.x + MW.y * B0.x + MW.z * C0.x + MW.w * D0.x;              \
      s1_ = MW.x * A0.y + MW.y * B0.y + MW.z * C0.y + MW.w * D0.y;              \
      s2_ = MW.x * A0.z + MW.y * B0.z + MW.z * C0.z + MW.w * D0.z;              \
      s3_ = MW.x * A0.w + MW.y * B0.w + MW.z * C0.w + MW.w * D0.w;              \
      s4_ = MW.x * A1.x + MW.y * B1.x + MW.z * C1.x + MW.w * D1.x;              \
      s5_ = MW.x * A1.y + MW.y * B1.y + MW.z * C1.y + MW.w * D1.y;              \
      s6_ = MW.x * A1.z + MW.y * B1.z + MW.z * C1.z + MW.w * D1.z;              \
      s7_ = MW.x * A1.w + MW.y * B1.w + MW.z * C1.w + MW.w * D1.w;              \
    } else {                                                                    \
      const float* xc_ = xb + (size_t)c8 * HW;                                  \
      s0_ = MW.x * xc_[MI.x] + MW.y * xc_[MI.y] + MW.z * xc_[MI.z] + MW.w * xc_[MI.w]; \
      xc_ += HW;                                                                \
      s1_ = MW.x * xc_[MI.x] + MW.y * xc_[MI.y] + MW.z * xc_[MI.z] + MW.w * xc_[MI.w]; \
      xc_ += HW;                                                                \
      s2_ = MW.x * xc_[MI.x] + MW.y * xc_[MI.y] + MW.z * xc_[MI.z] + MW.w * xc_[MI.w]; \
      xc_ += HW;                                                                \
      s3_ = MW.x * xc_[MI.x] + MW.y * xc_[MI.y] + MW.z * xc_[MI.z] + MW.w * xc_[MI.w]; \
      xc_ += HW;                                                                \
      s4_ = MW.x * xc_[MI.x] + MW.y * xc_[MI.y] + MW.z * xc_[MI.z] + MW.w * xc_[MI.w]; \
      xc_ += HW;                                                                \
      s5_ = MW.x * xc_[MI.x] + MW.y * xc_[MI.y] + MW.z * xc_[MI.z] + MW.w * xc_[MI.w]; \
      xc_ += HW;                                                                \
      s6_ = MW.x * xc_[MI.x] + MW.y * xc_[MI.y] + MW.z * xc_[MI.z] + MW.w * xc_[MI.w]; \
      xc_ += HW;                                                                \
      s7_ = MW.x * xc_[MI.x] + MW.y * xc_[MI.y] + MW.z * xc_[MI.z] + MW.w * xc_[MI.w]; \
    }                                                                           \
    unsigned u0_ = __float_as_uint(s0_) + 0x8000u;                              \
    unsigned u1_ = __float_as_uint(s1_) + 0x8000u;                              \
    unsigned u2_ = __float_as_uint(s2_) + 0x8000u;                              \
    unsigned u3_ = __float_as_uint(s3_) + 0x8000u;                              \
    unsigned u4_ = __float_as_uint(s4_) + 0x8000u;                              \
    unsigned u5_ = __float_as_uint(s5_) + 0x8000u;                              \
    unsigned u6_ = __float_as_uint(s6_) + 0x8000u;                              \
    unsigned u7_ = __float_as_uint(s7_) + 0x8000u;                              \
    uint4 pk_;                                                                  \
    pk_.x = (u0_ >> 16) | (u1_ & 0xFFFF0000u);                                  \
    pk_.y = (u2_ >> 16) | (u3_ & 0xFFFF0000u);                                  \
    pk_.z = (u4_ >> 16) | (u5_ & 0xFFFF0000u);                                  \
    pk_.w = (u6_ >> 16) | (u7_ & 0xFFFF0000u);                                  \
    int quad_ = (((ROW) >> 2) + step) & 3;                                      \
    *(uint4*)&sbuf[(ROW) * 16 + quad_ * 4] = pk_;                               \
  }

  for (int chunk = 0; chunk < CPC / 32; ++chunk) {
    int cbase = c0 + chunk * 32;
    for (int step = 0; step < 4; ++step) {
      int c8 = cbase + step * 8;
      {
        const float* xsb = xb + (size_t)(c8 + (t & 7)) * HW + ob + (t >> 3);
        int ldsbase = t & ~63;    // wave-uniform
#pragma unroll
        for (int j = 0; j < 16; ++j)
          __builtin_amdgcn_global_load_lds(
              (const __attribute__((address_space(1))) void*)(xsb + j * 32),
              (__attribute__((address_space(3))) void*)&win[j * 256 + ldsbase],
              4, 0, 0);
      }
      __syncthreads();
      GATHER(mw0, mi0, fast0, t)
      GATHER(mw1, mi1, fast1, 256 + t)
      if (hasC) GATHER(mw2, mi2, fast2, 512 + t)
      __syncthreads();
    }

    __builtin_amdgcn_s_setprio(1);
#pragma unroll
    for (int k = 0; k < 9; ++k) {
      short8v bh[4];
#pragma unroll
      for (int nt = 0; nt < 4; ++nt) {
        int row = k * 64 + nt * 16 + lrow;
        int quad = ((row >> 2) + lgrp) & 3;
        bh[nt] = *(const short8v*)&sbuf[row * 16 + quad * 4];
      }
#pragma unroll
      for (int m = 0; m < 2; ++m) {
        size_t widx = (((size_t)k * 32 + (cbase >> 3) + lgrp) * 128 + (wv * 32 + m * 16 + lrow)) * 8;
        short8v ah = *(const short8v*)(w_hi + widx);
        short8v al = *(const short8v*)(w_lo + widx);
#pragma unroll
        for (int nt = 0; nt < 4; ++nt) {
          acc[m][nt] = __builtin_amdgcn_mfma_f32_16x16x32_bf16(ah, bh[nt], acc[m][nt], 0, 0, 0);
          acc[m][nt] = __builtin_amdgcn_mfma_f32_16x16x32_bf16(al, bh[nt], acc[m][nt], 0, 0, 0);
        }
      }
    }
    __builtin_amdgcn_s_setprio(0);
    __syncthreads();
  }
#undef GATHER

#pragma unroll
  for (int m = 0; m < 2; ++m)
#pragma unroll
    for (int nt = 0; nt < 4; ++nt)
#pragma unroll
      for (int j = 0; j < 4; ++j) {
        int co = wv * 32 + m * 16 + lgrp * 4 + j;
        int p = h * 64 + nt * 16 + lrow;
        part[(((size_t)s2 * NB + b) * COUT + co) * HW + p] = acc[m][nt][j];
      }
}

// ---------------- fused reduce + bias + relu + 2x bilinear upsample
// j-pair tiled (R29/R31, validated) + XCD swizzle (grid 16384 = 8 x 2048).
__global__ __launch_bounds__(256) void k_upred(
    const float* __restrict__ part, const float* __restrict__ bias_t,
    float* __restrict__ out)
{
  int bid = (blockIdx.x & 7) * 2048 + (blockIdx.x >> 3);  // bijective: 16384 = 8*2048
  int t = bid * 256 + threadIdx.x;
  if (t >= NB * COUT * 128 * 64) return;
  int q = t & 63;
  int i = (t >> 6) & 127;
  int bc = t >> 13;                 // b*COUT + co
  int co = bc & (COUT - 1);
  const float R = (float)(63.0 / 127.0);
  float pi = (float)i * R;
  float i0f = floorf(pi);
  int i0 = (int)i0f;
  int i1 = min(i0 + 1, 63);
  float f = pi - i0f;

  const float* p0 = part + (size_t)bc * HW;
  const float* p1 = part + (size_t)(CSPLIT - 1) * NB * COUT * HW + (size_t)bc * HW;
  const float* r00 = p0 + i0 * 64;
  const float* r01 = p0 + i1 * 64;
  const float* r10 = p1 + i0 * 64;
  const float* r11 = p1 + i1 * 64;
  float bv = bias_t[co];

  float2 res;
#pragma unroll
  for (int e = 0; e < 2; ++e) {
    int j = 2 * q + e;
    float pj = (float)j * R;
    float j0f = floorf(pj);
    int j0 = (int)j0f;
    int j1 = min(j0 + 1, 63);
    float g = pj - j0f;
    float a  = fmaxf(r00[j0] + r10[j0] + bv, 0.f);
    float bb = fmaxf(r00[j1] + r10[j1] + bv, 0.f);
    float cc = fmaxf(r01[j0] + r11[j0] + bv, 0.f);
    float dd = fmaxf(r01[j1] + r11[j1] + bv, 0.f);
    float t0 = a * (1.f - f) + cc * f;
    float t1 = bb * (1.f - f) + dd * f;
    float v = t0 * (1.f - g) + t1 * g;
    if (e == 0) res.x = v; else res.y = v;
  }
  *(float2*)&out[(size_t)bc * 16384 + i * 128 + 2 * q] = res;
}

extern "C" void kernel_launch(void* const* d_in, const int* in_sizes, int n_in,
                              void* d_out, int out_size, void* d_ws, size_t ws_size,
                              hipStream_t stream)
{
  const float* x     = (const float*)d_in[0];
  const float* w_off = (const float*)d_in[1];
  const float* b_off = (const float*)d_in[2];
  const float* w_dcn = (const float*)d_in[3];
  const float* b_dcn = (const float*)d_in[4];
  const float* gamma = (const float*)d_in[5];
  const float* beta  = (const float*)d_in[6];
  const float* rmean = (const float*)d_in[7];
  const float* rvar  = (const float*)d_in[8];
  float* out = (float*)d_out;

  char* ws = (char*)d_ws;
  size_t off = 0;
  auto alloc = [&](size_t bytes) {
    void* p = ws + off;
    off = (off + bytes + 255) & ~255UL;
    return p;
  };
  float*  om_part = (float*) alloc(sizeof(float)  * OCSPLIT * NB * 27 * HW);
  unsigned short* w_hi = (unsigned short*)alloc(sizeof(unsigned short) * 9 * CIN * COUT);
  unsigned short* w_lo = (unsigned short*)alloc(sizeof(unsigned short) * 9 * CIN * COUT);
  unsigned short* wo_hi = (unsigned short*)alloc(sizeof(unsigned short) * 9 * 32 * 32 * 8);
  unsigned short* wo_lo = (unsigned short*)alloc(sizeof(unsigned short) * 9 * 32 * 32 * 8);
  float*  bias_t  = (float*) alloc(sizeof(float)  * COUT);
  float*  part    = (float*) alloc(sizeof(float)  * CSPLIT * NB * COUT * HW);
  (void)ws_size; (void)in_sizes; (void)n_in; (void)out_size;

  k_prep<<<(CIN * COUT * 9 + 255) / 256, 256, 0, stream>>>(
      w_dcn, b_dcn, gamma, beta, rmean, rvar, w_off, w_hi, w_lo, wo_hi, wo_lo, bias_t);
  k_off_mfma<<<NB * 64 * 4, 256, 0, stream>>>(x, wo_hi, wo_lo, om_part);
  k_dcn<<<CSPLIT * NB * 64, 256, 0, stream>>>(x, w_hi, w_lo, om_part, b_off, part);
  k_upred<<<(NB * COUT * 128 * 64 + 255) / 256, 256, 0, stream>>>(part, bias_t, out);
}

// Round 35
// 96.490 us; speedup vs baseline: 1.0334x; 1.0334x over previous
//
#include <hip/hip_runtime.h>
#include <math.h>

#define CIN  256
#define COUT 128
#define HW   4096
#define NB   4
#define OCSPLIT 4
#define CSPLIT  2
#define CPC  (CIN / CSPLIT)      // 128 channels per k_dcn block (4 chunks of 32)
#define SFLAV (576 * 16)         // u32 words in k_dcn sbuf (hi flavor only)

typedef short short8v __attribute__((ext_vector_type(8)));
typedef float f32x4  __attribute__((ext_vector_type(4)));

// ---------------- merged weight prep: DCN hi/lo split + offset-conv pack + bias
__global__ __launch_bounds__(256) void k_prep(
    const float* __restrict__ w_dcn, const float* __restrict__ b_dcn,
    const float* __restrict__ gamma, const float* __restrict__ beta,
    const float* __restrict__ rmean, const float* __restrict__ rvar,
    const float* __restrict__ w_off,
    unsigned short* __restrict__ w_hi, unsigned short* __restrict__ w_lo,
    unsigned short* __restrict__ wo_hi, unsigned short* __restrict__ wo_lo,
    float* __restrict__ bias_t)
{
  int t = blockIdx.x * 256 + threadIdx.x;
  if (t < COUT) {
    float sc = gamma[t] * rsqrtf(rvar[t] + 1e-5f);
    bias_t[t] = b_dcn[t] * sc + beta[t] - rmean[t] * sc;
  }
  if (t < 9 * 32 * 32 * 8) {   // offset-conv weights: [k][cq][co32][8ch], co>=27 zero
    int ce = t & 7;
    int co = (t >> 3) & 31;
    int cq = (t >> 8) & 31;
    int k  = t >> 13;
    int c = cq * 8 + ce;
    float w = (co < 27) ? w_off[((size_t)co * CIN + c) * 9 + k] : 0.f;
    unsigned int wb = __float_as_uint(w);
    unsigned short hi = (unsigned short)(wb >> 16);
    float lof = w - __uint_as_float(wb & 0xFFFF0000u);
    unsigned short lo = (unsigned short)(__float_as_uint(lof) >> 16);
    wo_hi[t] = hi;
    wo_lo[t] = lo;
  }
  if (t >= CIN * COUT * 9) return;
  int k = t % 9;
  int q = t / 9;
  int co = q % COUT;
  int c  = q / COUT;
  float sc = gamma[co] * rsqrtf(rvar[co] + 1e-5f);
  float w = w_dcn[((size_t)co * CIN + c) * 9 + k] * sc;
  unsigned int wb = __float_as_uint(w);
  unsigned short hi = (unsigned short)(wb >> 16);
  float lof = w - __uint_as_float(wb & 0xFFFF0000u);
  unsigned short lo = (unsigned short)(__float_as_uint(lof) >> 16);
  size_t idx = (((size_t)k * 32 + (c >> 3)) * 128 + co) * 8 + (c & 7);
  w_hi[idx] = hi;
  w_lo[idx] = lo;
}

// ---------------- offset conv via MFMA: x rounded bf16 (2-term), W hi/lo split
// + XCD swizzle (grid 1024 = 8 x 128). LDS 15840 B.  (R30, validated)
__global__ __launch_bounds__(256, 4) void k_off_mfma(
    const float* __restrict__ x,
    const unsigned short* __restrict__ wo_hi, const unsigned short* __restrict__ wo_lo,
    float* __restrict__ om_part)
{
  int blk = (blockIdx.x & 7) * 128 + (blockIdx.x >> 3);  // bijective: 1024 = 8*128
  int split = blk & 3;
  int bh = blk >> 2;
  int b = bh >> 6, h = bh & 63;
  int t = threadIdx.x;
  int lane = t & 63;
  int wv = t >> 6;
  int lrow = lane & 15, lgrp = lane >> 4;

  __shared__ __align__(16) unsigned int win_hi[3 * 66 * 20];  // 15840 B

  f32x4 acc[2];
  acc[0] = (f32x4){0.f, 0.f, 0.f, 0.f};
  acc[1] = (f32x4){0.f, 0.f, 0.f, 0.f};

  const float* xb = x + (size_t)b * CIN * HW;

  for (int chunk = 0; chunk < 2; ++chunk) {
    int cbase = split * 64 + chunk * 32;
    for (int i = t; i < 3168; i += 256) {
      int cp = i / 198;
      int s  = i - cp * 198;
      int r  = s / 66;
      int colp = s - r * 66;
      int row = h + r - 1;
      int col = colp - 1;
      bool v = ((unsigned)row < 64u) && ((unsigned)col < 64u);
      int ch = cbase + 2 * cp;
      float f0 = 0.f, f1 = 0.f;
      if (v) {
        const float* xp = xb + ((size_t)ch * 64 + row) * 64 + col;
        f0 = xp[0];
        f1 = xp[HW];
      }
      unsigned a0 = __float_as_uint(f0) + 0x8000u;   // round-to-nearest bf16
      unsigned a1 = __float_as_uint(f1) + 0x8000u;
      win_hi[s * 20 + cp] = (a0 >> 16) | (a1 & 0xFFFF0000u);
    }
    __syncthreads();

    int pos = wv * 16 + lrow;
#pragma unroll
    for (int k = 0; k < 9; ++k) {
      int ky = k / 3 - 1, kx = k % 3 - 1;
      int slot = (ky + 1) * 66 + pos + kx + 1;
      short8v bhv = *(const short8v*)&win_hi[slot * 20 + lgrp * 4];
#pragma unroll
      for (int m = 0; m < 2; ++m) {
        size_t widx = (((size_t)k * 32 + (cbase >> 3) + lgrp) * 32 + m * 16 + lrow) * 8;
        short8v ah = *(const short8v*)(wo_hi + widx);
        short8v al = *(const short8v*)(wo_lo + widx);
        acc[m] = __builtin_amdgcn_mfma_f32_16x16x32_bf16(ah, bhv, acc[m], 0, 0, 0);
        acc[m] = __builtin_amdgcn_mfma_f32_16x16x32_bf16(al, bhv, acc[m], 0, 0, 0);
      }
    }
    __syncthreads();
  }

  int pos = wv * 16 + lrow;
#pragma unroll
  for (int m = 0; m < 2; ++m)
#pragma unroll
    for (int j = 0; j < 4; ++j) {
      int co = m * 16 + lgrp * 4 + j;
      if (co < 27)
        om_part[(((size_t)split * NB + b) * 27 + co) * HW + h * 64 + pos] = acc[m][j];
    }
}

// ---------------- DCN: P=64 channel-last LDS window + MFMA (R31/R33, validated)
// md computed INLINE from om_part (bit-identical k_prep_md arithmetic).
__global__ __launch_bounds__(256, 3) void k_dcn(
    const float* __restrict__ x,
    const unsigned short* __restrict__ w_hi, const unsigned short* __restrict__ w_lo,
    const float* __restrict__ om_part, const float* __restrict__ b_off,
    float* __restrict__ part)
{
  int blk = (blockIdx.x & 7) * 64 + (blockIdx.x >> 3);  // bijective: 512 = 8*64
  int h = blk & 63;
  int b = (blk >> 6) & (NB - 1);
  int s2 = blk >> 8;
  int c0 = s2 * CPC;
  int t = threadIdx.x;
  int lane = t & 63;
  int wv = t >> 6;
  int lrow = lane & 15, lgrp = lane >> 4;

  __shared__ __align__(16) unsigned int sbuf[SFLAV];      // 36864 B (hi only)
  __shared__ __align__(16) float win[8 * 64 * 4];         // 8192 B, channel-last

  int W0 = min(max(h - 3, 0), 56);
  int ob = W0 * 64;

#define MDCALC(K, POS, MW, MI)                                                  \
  {                                                                             \
    int k_ = (K);                                                               \
    int hw_ = h * 64 + (POS);                                                   \
    int w_ = hw_ & 63;                                                          \
    float dy = b_off[2 * k_], dx = b_off[2 * k_ + 1], mr = b_off[18 + k_];      \
    _Pragma("unroll")                                                           \
    for (int s_ = 0; s_ < OCSPLIT; ++s_) {                                      \
      size_t o_ = ((size_t)s_ * NB + b) * 27 * HW + hw_;                        \
      dy += om_part[o_ + (size_t)(2 * k_) * HW];                                \
      dx += om_part[o_ + (size_t)(2 * k_ + 1) * HW];                            \
      mr += om_part[o_ + (size_t)(18 + k_) * HW];                               \
    }                                                                           \
    float m_ = 1.0f / (1.0f + expf(-mr));                                       \
    int ky_ = k_ / 3 - 1, kx_ = k_ % 3 - 1;                                     \
    float py_ = dy + (float)h + (float)ky_;                                     \
    float px_ = dx + (float)w_ + (float)kx_;                                    \
    float y0f_ = floorf(py_), x0f_ = floorf(px_);                               \
    float fy_ = py_ - y0f_, fx_ = px_ - x0f_;                                   \
    int y0_ = (int)y0f_, x0_ = (int)x0f_;                                       \
    int y1_ = y0_ + 1, x1_ = x0_ + 1;                                           \
    bool vy0_ = (y0_ >= 0) & (y0_ < 64), vy1_ = (y1_ >= 0) & (y1_ < 64);        \
    bool vx0_ = (x0_ >= 0) & (x0_ < 64), vx1_ = (x1_ >= 0) & (x1_ < 64);        \
    int cy0_ = min(max(y0_, 0), 63), cy1_ = min(max(y1_, 0), 63);               \
    int cx0_ = min(max(x0_, 0), 63), cx1_ = min(max(x1_, 0), 63);               \
    MW.x = (vy0_ && vx0_) ? (1.f - fy_) * (1.f - fx_) * m_ : 0.f;               \
    MW.y = (vy0_ && vx1_) ? (1.f - fy_) * fx_ * m_ : 0.f;                       \
    MW.z = (vy1_ && vx0_) ? fy_ * (1.f - fx_) * m_ : 0.f;                       \
    MW.w = (vy1_ && vx1_) ? fy_ * fx_ * m_ : 0.f;                               \
    MI.x = cy0_ * 64 + cx0_;                                                    \
    MI.y = cy0_ * 64 + cx1_;                                                    \
    MI.z = cy1_ * 64 + cx0_;                                                    \
    MI.w = cy1_ * 64 + cx1_;                                                    \
  }

  int k0 = t >> 6;
  float4 mw0; int4 mi0;
  float4 mw1; int4 mi1;
  MDCALC(k0, (t & 63), mw0, mi0)
  MDCALC(k0 + 4, (t & 63), mw1, mi1)
  bool hasC = (t < 64);
  float4 mw2 = make_float4(0.f, 0.f, 0.f, 0.f);
  int4  mi2 = make_int4(0, 0, 0, 0);
  if (hasC) MDCALC(8, t, mw2, mi2)
#undef MDCALC

  int fast0 = __all(((unsigned)(mi0.x - ob) < 512u) && ((unsigned)(mi0.z - ob) < 512u));
  int fast1 = __all(((unsigned)(mi1.x - ob) < 512u) && ((unsigned)(mi1.z - ob) < 512u));
  int fast2 = __all(((unsigned)(mi2.x - ob) < 512u) && ((unsigned)(mi2.z - ob) < 512u));

  f32x4 acc[2][4];
#pragma unroll
  for (int m = 0; m < 2; ++m)
#pragma unroll
    for (int nt = 0; nt < 4; ++nt)
      acc[m][nt] = (f32x4){0.f, 0.f, 0.f, 0.f};

  const float* xb = x + (size_t)b * CIN * HW;

#define GATHER(MW, MI, FASTE, ROW)                                              \
  {                                                                             \
    float s0_, s1_, s2_, s3_;                                                   \
    if (FASTE) {                                                                \
      float4 T0 = *(const float4*)&win[(MI.x - ob) * 4];                        \
      float4 T1 = *(const float4*)&win[(MI.y - ob) * 4];                        \
      float4 T2 = *(const float4*)&win[(MI.z - ob) * 4];                        \
      float4 T3 = *(const float4*)&win[(MI.w - ob) * 4];                        \
      s0_ = MW.x * T0.x + MW.y * T1.x + MW.z * T2.x + MW.w * T3.x;              \
      s1_ = MW.x * T0.y + MW.y * T1.y + MW.z * T2.y + MW.w * T3.y;              \
      s2_ = MW.x * T0.z + MW.y * T1.z + MW.z * T2.z + MW.w * T3.z;              \
      s3_ = MW.x * T0.w + MW.y * T1.w + MW.z * T2.w + MW.w * T3.w;              \
    } else {                                                                    \
      const float* xc_ = xb + (size_t)c4 * HW;                                  \
      s0_ = MW.x * xc_[MI.x] + MW.y * xc_[MI.y] + MW.z * xc_[MI.z] + MW.w * xc_[MI.w]; \
      xc_ += HW;                                                                \
      s1_ = MW.x * xc_[MI.x] + MW.y * xc_[MI.y] + MW.z * xc_[MI.z] + MW.w * xc_[MI.w]; \
      xc_ += HW;                                                                \
      s2_ = MW.x * xc_[MI.x] + MW.y * xc_[MI.y] + MW.z * xc_[MI.z] + MW.w * xc_[MI.w]; \
      xc_ += HW;                                                                \
      s3_ = MW.x * xc_[MI.x] + MW.y * xc_[MI.y] + MW.z * xc_[MI.z] + MW.w * xc_[MI.w]; \
    }                                                                           \
    unsigned a0_ = __float_as_uint(s0_) + 0x8000u;                              \
    unsigned a1_ = __float_as_uint(s1_) + 0x8000u;                              \
    unsigned a2_ = __float_as_uint(s2_) + 0x8000u;                              \
    unsigned a3_ = __float_as_uint(s3_) + 0x8000u;                              \
    unsigned hiA_ = (a0_ >> 16) | (a1_ & 0xFFFF0000u);                          \
    unsigned hiB_ = (a2_ >> 16) | (a3_ & 0xFFFF0000u);                          \
    int cp0_ = 2 * step;                                                        \
    int quad_ = (((ROW) >> 2) + (cp0_ >> 2)) & 3;                               \
    int word_ = (ROW) * 16 + quad_ * 4 + (cp0_ & 3);                            \
    *(uint2*)&sbuf[word_] = make_uint2(hiA_, hiB_);                             \
  }

  for (int chunk = 0; chunk < CPC / 32; ++chunk) {
    int cbase = c0 + chunk * 32;
    for (int step = 0; step < 8; ++step) {
      int c4 = cbase + step * 4;
      {
        const float* xsb = xb + (size_t)(c4 + (t & 3)) * HW + ob + (t >> 2);
        int ldsbase = t & ~63;    // wave-uniform
#pragma unroll
        for (int j = 0; j < 8; ++j)
          __builtin_amdgcn_global_load_lds(
              (const __attribute__((address_space(1))) void*)(xsb + j * 64),
              (__attribute__((address_space(3))) void*)&win[j * 256 + ldsbase],
              4, 0, 0);
      }
      __syncthreads();
      GATHER(mw0, mi0, fast0, t)
      GATHER(mw1, mi1, fast1, 256 + t)
      if (hasC) GATHER(mw2, mi2, fast2, 512 + t)
      __syncthreads();
    }

    __builtin_amdgcn_s_setprio(1);
#pragma unroll
    for (int k = 0; k < 9; ++k) {
      short8v bh[4];
#pragma unroll
      for (int nt = 0; nt < 4; ++nt) {
        int row = k * 64 + nt * 16 + lrow;
        int quad = ((row >> 2) + lgrp) & 3;
        bh[nt] = *(const short8v*)&sbuf[row * 16 + quad * 4];
      }
#pragma unroll
      for (int m = 0; m < 2; ++m) {
        size_t widx = (((size_t)k * 32 + (cbase >> 3) + lgrp) * 128 + (wv * 32 + m * 16 + lrow)) * 8;
        short8v ah = *(const short8v*)(w_hi + widx);
        short8v al = *(const short8v*)(w_lo + widx);
#pragma unroll
        for (int nt = 0; nt < 4; ++nt) {
          acc[m][nt] = __builtin_amdgcn_mfma_f32_16x16x32_bf16(ah, bh[nt], acc[m][nt], 0, 0, 0);
          acc[m][nt] = __builtin_amdgcn_mfma_f32_16x16x32_bf16(al, bh[nt], acc[m][nt], 0, 0, 0);
        }
      }
    }
    __builtin_amdgcn_s_setprio(0);
    __syncthreads();
  }
#undef GATHER

#pragma unroll
  for (int m = 0; m < 2; ++m)
#pragma unroll
    for (int nt = 0; nt < 4; ++nt)
#pragma unroll
      for (int j = 0; j < 4; ++j) {
        int co = wv * 32 + m * 16 + lgrp * 4 + j;
        int p = h * 64 + nt * 16 + lrow;
        part[(((size_t)s2 * NB + b) * COUT + co) * HW + p] = acc[m][nt][j];
      }
}

// ---------------- fused reduce + bias + relu + 2x bilinear upsample
// j-pair tiled (R29/R31, validated) + XCD swizzle (grid 16384 = 8 x 2048).
__global__ __launch_bounds__(256) void k_upred(
    const float* __restrict__ part, const float* __restrict__ bias_t,
    float* __restrict__ out)
{
  int bid = (blockIdx.x & 7) * 2048 + (blockIdx.x >> 3);  // bijective: 16384 = 8*2048
  int t = bid * 256 + threadIdx.x;
  if (t >= NB * COUT * 128 * 64) return;
  int q = t & 63;
  int i = (t >> 6) & 127;
  int bc = t >> 13;                 // b*COUT + co
  int co = bc & (COUT - 1);
  const float R = (float)(63.0 / 127.0);
  float pi = (float)i * R;
  float i0f = floorf(pi);
  int i0 = (int)i0f;
  int i1 = min(i0 + 1, 63);
  float f = pi - i0f;

  const float* p0 = part + (size_t)bc * HW;
  const float* p1 = part + (size_t)(CSPLIT - 1) * NB * COUT * HW + (size_t)bc * HW;
  const float* r00 = p0 + i0 * 64;
  const float* r01 = p0 + i1 * 64;
  const float* r10 = p1 + i0 * 64;
  const float* r11 = p1 + i1 * 64;
  float bv = bias_t[co];

  float2 res;
#pragma unroll
  for (int e = 0; e < 2; ++e) {
    int j = 2 * q + e;
    float pj = (float)j * R;
    float j0f = floorf(pj);
    int j0 = (int)j0f;
    int j1 = min(j0 + 1, 63);
    float g = pj - j0f;
    float a  = fmaxf(r00[j0] + r10[j0] + bv, 0.f);
    float bb = fmaxf(r00[j1] + r10[j1] + bv, 0.f);
    float cc = fmaxf(r01[j0] + r11[j0] + bv, 0.f);
    float dd = fmaxf(r01[j1] + r11[j1] + bv, 0.f);
    float t0 = a * (1.f - f) + cc * f;
    float t1 = bb * (1.f - f) + dd * f;
    float v = t0 * (1.f - g) + t1 * g;
    if (e == 0) res.x = v; else res.y = v;
  }
  *(float2*)&out[(size_t)bc * 16384 + i * 128 + 2 * q] = res;
}

extern "C" void kernel_launch(void* const* d_in, const int* in_sizes, int n_in,
                              void* d_out, int out_size, void* d_ws, size_t ws_size,
                              hipStream_t stream)
{
  const float* x     = (const float*)d_in[0];
  const float* w_off = (const float*)d_in[1];
  const float* b_off = (const float*)d_in[2];
  const float* w_dcn = (const float*)d_in[3];
  const float* b_dcn = (const float*)d_in[4];
  const float* gamma = (const float*)d_in[5];
  const float* beta  = (const float*)d_in[6];
  const float* rmean = (const float*)d_in[7];
  const float* rvar  = (const float*)d_in[8];
  float* out = (float*)d_out;

  char* ws = (char*)d_ws;
  size_t off = 0;
  auto alloc = [&](size_t bytes) {
    void* p = ws + off;
    off = (off + bytes + 255) & ~255UL;
    return p;
  };
  float*  om_part = (float*) alloc(sizeof(float)  * OCSPLIT * NB * 27 * HW);
  unsigned short* w_hi = (unsigned short*)alloc(sizeof(unsigned short) * 9 * CIN * COUT);
  unsigned short* w_lo = (unsigned short*)alloc(sizeof(unsigned short) * 9 * CIN * COUT);
  unsigned short* wo_hi = (unsigned short*)alloc(sizeof(unsigned short) * 9 * 32 * 32 * 8);
  unsigned short* wo_lo = (unsigned short*)alloc(sizeof(unsigned short) * 9 * 32 * 32 * 8);
  float*  bias_t  = (float*) alloc(sizeof(float)  * COUT);
  float*  part    = (float*) alloc(sizeof(float)  * CSPLIT * NB * COUT * HW);
  (void)ws_size; (void)in_sizes; (void)n_in; (void)out_size;

  k_prep<<<(CIN * COUT * 9 + 255) / 256, 256, 0, stream>>>(
      w_dcn, b_dcn, gamma, beta, rmean, rvar, w_off, w_hi, w_lo, wo_hi, wo_lo, bias_t);
  k_off_mfma<<<NB * 64 * 4, 256, 0, stream>>>(x, wo_hi, wo_lo, om_part);
  k_dcn<<<CSPLIT * NB * 64, 256, 0, stream>>>(x, w_hi, w_lo, om_part, b_off, part);
  k_upred<<<(NB * COUT * 128 * 64 + 255) / 256, 256, 0, stream>>>(part, bias_t, out);
}